// Round 2
// baseline (13239.093 us; speedup 1.0000x reference)
//
#include <hip/hip_runtime.h>

#define N_NODES 100000
#define N_EDGES 800000
#define HDIM 100

constexpr int KC = 32;      // K-chunk
constexpr int ROWS = 256;   // rows per block tile

// Generic register-blocked GEMM:  C[M,NC] = epilogue(A[M,K] @ W[K,NC] + bias)
// MODE:   0 = store, 1 = relu+store, 2 = C = C + 0.5*v (edge residual update)
// GATHER: 0 = plain A;  1 = A row m = cat(h[src[m]], h[dst[m]], e[m]) (K=300)
//         2 = same as 1 but relu() applied to the h segments (final feat)
// VEC4:   float4 A loads (requires K%4==0); only used when GATHER==0
template<int NC, int NCP, int MODE, int GATHER, bool VEC4>
__global__ __launch_bounds__(256)
void gemm_k(const float* __restrict__ A, const float* __restrict__ W,
            const float* __restrict__ bias, float* __restrict__ C,
            int M, int K,
            const int* __restrict__ src, const int* __restrict__ dst,
            const float* __restrict__ hbuf, const float* __restrict__ ebuf)
{
    constexpr int CPT = NCP / 4;        // cols per thread (4 col-groups)
    static_assert(NCP % 16 == 0, "NCP must be multiple of 16");
    __shared__ float As[KC][ROWS + 4];  // transposed A tile, padded
    __shared__ float Ws[KC][NCP];

    const int tid  = threadIdx.x;
    const int lane = tid & 63;
    const int g    = tid >> 6;          // wave id == column group
    const long row0 = (long)blockIdx.x * ROWS;

    float acc[4][CPT];
#pragma unroll
    for (int r = 0; r < 4; ++r)
#pragma unroll
        for (int c = 0; c < CPT; ++c) acc[r][c] = 0.f;

    for (int k0 = 0; k0 < K; k0 += KC) {
        // ---- load A tile (transposed into LDS) ----
        if (GATHER == 0) {
            if (VEC4) {
#pragma unroll
                for (int j = 0; j < 8; ++j) {
                    int idx4 = tid + j * 256;          // 2048 quads
                    int rr = idx4 >> 3;
                    int c4 = (idx4 & 7) * 4;
                    long grow = row0 + rr;
                    float4 v = make_float4(0.f, 0.f, 0.f, 0.f);
                    if (grow < M && (k0 + c4) < K)
                        v = *(const float4*)&A[grow * (long)K + k0 + c4];
                    As[c4 + 0][rr] = v.x; As[c4 + 1][rr] = v.y;
                    As[c4 + 2][rr] = v.z; As[c4 + 3][rr] = v.w;
                }
            } else {
#pragma unroll
                for (int j = 0; j < 32; ++j) {
                    int idx = tid + j * 256;           // 8192 scalars
                    int rr = idx >> 5;
                    int cc = idx & 31;
                    long grow = row0 + rr;
                    float v = 0.f;
                    if (grow < M && (k0 + cc) < K)
                        v = A[grow * (long)K + k0 + cc];
                    As[cc][rr] = v;
                }
            }
        } else {
            // gathered cat(h[src], h[dst], e) — segment boundaries (100,200) are 4-aligned
#pragma unroll
            for (int j = 0; j < 8; ++j) {
                int idx4 = tid + j * 256;
                int rr = idx4 >> 3;
                int c4 = (idx4 & 7) * 4;
                long grow = row0 + rr;                 // edge id
                int col = k0 + c4;
                float4 v = make_float4(0.f, 0.f, 0.f, 0.f);
                if (grow < M && col < K) {
                    int seg = (col >= 200) ? 2 : (col >= 100 ? 1 : 0);
                    int off = col - seg * 100;
                    long r = (seg == 0) ? (long)src[grow]
                           : (seg == 1) ? (long)dst[grow] : grow;
                    const float* base = (seg == 2) ? ebuf : hbuf;
                    v = *(const float4*)&base[r * HDIM + off];
                    if (GATHER == 2 && seg < 2) {
                        v.x = fmaxf(v.x, 0.f); v.y = fmaxf(v.y, 0.f);
                        v.z = fmaxf(v.z, 0.f); v.w = fmaxf(v.w, 0.f);
                    }
                }
                As[c4 + 0][rr] = v.x; As[c4 + 1][rr] = v.y;
                As[c4 + 2][rr] = v.z; As[c4 + 3][rr] = v.w;
            }
        }
        // ---- load W tile ----
#pragma unroll
        for (int j = tid; j < KC * NCP; j += 256) {
            int kk = j / NCP;
            int cc = j % NCP;
            float v = 0.f;
            if (cc < NC && (k0 + kk) < K)
                v = W[(long)(k0 + kk) * NC + cc];
            Ws[kk][cc] = v;
        }
        __syncthreads();

        // ---- FMA inner loop: 4 rows x CPT cols per thread ----
#pragma unroll
        for (int kk = 0; kk < KC; ++kk) {
            float4 a = *(const float4*)&As[kk][lane * 4];
            float av[4] = {a.x, a.y, a.z, a.w};
#pragma unroll
            for (int q = 0; q < CPT / 4; ++q) {
                float4 w = *(const float4*)&Ws[kk][g * CPT + q * 4];
                float wv[4] = {w.x, w.y, w.z, w.w};
#pragma unroll
                for (int r = 0; r < 4; ++r) {
#pragma unroll
                    for (int i = 0; i < 4; ++i)
                        acc[r][q * 4 + i] += av[r] * wv[i];
                }
            }
        }
        __syncthreads();
    }

    // ---- epilogue ----
#pragma unroll
    for (int r = 0; r < 4; ++r) {
        long grow = row0 + lane * 4 + r;
        if (grow >= M) continue;
#pragma unroll
        for (int c = 0; c < CPT; ++c) {
            int col = g * CPT + c;
            if (col < NC) {
                float v = acc[r][c] + bias[col];
                if (MODE == 1) v = fmaxf(v, 0.f);
                long o = grow * (long)NC + col;
                if (MODE == 2) C[o] = C[o] + 0.5f * v;
                else           C[o] = v;
            }
        }
    }
}

// msg = relu(h[src] + lin_e);  agg[dst] += msg   (agg pre-initialized with h)
__global__ __launch_bounds__(256)
void msg_scatter_k(const float* __restrict__ h, const float* __restrict__ tmp,
                   const int* __restrict__ src, const int* __restrict__ dst,
                   float* __restrict__ agg)
{
    unsigned idx = blockIdx.x * 256u + threadIdx.x;   // < E*100 = 80M
    unsigned m = idx / HDIM;
    unsigned c = idx - m * HDIM;
    int s = src[m], d = dst[m];
    float v = fmaxf(h[(long)s * HDIM + c] + tmp[idx], 0.f);
    atomicAdd(&agg[(long)d * HDIM + c], v);
}

// column sums / sums-of-squares for BatchNorm (stats[0:100]=sum, [100:200]=sumsq)
__global__ __launch_bounds__(128)
void bn_stats_k(const float* __restrict__ z, float* __restrict__ stats)
{
    int c = threadIdx.x;
    if (c >= HDIM) return;
    long rows_per = (N_NODES + gridDim.x - 1) / gridDim.x;
    long r0 = (long)blockIdx.x * rows_per;
    long r1 = r0 + rows_per; if (r1 > N_NODES) r1 = N_NODES;
    float s = 0.f, s2 = 0.f;
    for (long r = r0; r < r1; ++r) {
        float v = z[r * HDIM + c];
        s += v; s2 += v * v;
    }
    atomicAdd(&stats[c], s);
    atomicAdd(&stats[HDIM + c], s2);
}

// z = BN(z2)*gamma+beta ; h = (h + relu(z)) / 2
__global__ __launch_bounds__(256)
void bn_apply_k(const float* __restrict__ z, const float* __restrict__ stats,
                const float* __restrict__ gamma, const float* __restrict__ beta,
                float* __restrict__ h)
{
    unsigned idx = blockIdx.x * 256u + threadIdx.x;
    if (idx >= (unsigned)(N_NODES * HDIM)) return;
    unsigned c = idx % HDIM;
    const float invN = 1.f / N_NODES;
    float mu  = stats[c] * invN;
    float var = stats[HDIM + c] * invN - mu * mu;
    float v = (z[idx] - mu) * rsqrtf(var + 1e-5f) * gamma[c] + beta[c];
    h[idx] = (h[idx] + fmaxf(v, 0.f)) * 0.5f;
}

// out[E,2] = f2[E,25] @ mw3[25,2] + mb3
__global__ __launch_bounds__(256)
void final_out_k(const float* __restrict__ f2, const float* __restrict__ W,
                 const float* __restrict__ b, float* __restrict__ out)
{
    unsigned m = blockIdx.x * 256u + threadIdx.x;
    if (m >= N_EDGES) return;
    float a0 = b[0], a1 = b[1];
    const float* row = &f2[(long)m * 25];
#pragma unroll
    for (int k = 0; k < 25; ++k) {
        float v = row[k];
        a0 += v * W[k * 2 + 0];
        a1 += v * W[k * 2 + 1];
    }
    out[(long)m * 2 + 0] = a0;
    out[(long)m * 2 + 1] = a1;
}

static inline int gblocks(long m) { return (int)((m + ROWS - 1) / ROWS); }

extern "C" void kernel_launch(void* const* d_in, const int* in_sizes, int n_in,
                              void* d_out, int out_size, void* d_ws, size_t ws_size,
                              hipStream_t stream)
{
    const float* x         = (const float*)d_in[0];
    const int*   ei        = (const int*)  d_in[1];
    const float* edge_attr = (const float*)d_in[2];
    const float* node_w    = (const float*)d_in[3];
    const float* node_b    = (const float*)d_in[4];
    const float* edge_w    = (const float*)d_in[5];
    const float* edge_b    = (const float*)d_in[6];
    const float* lin_w     = (const float*)d_in[7];
    const float* lin_b     = (const float*)d_in[8];
    const float* w1        = (const float*)d_in[9];
    const float* b1        = (const float*)d_in[10];
    const float* w2        = (const float*)d_in[11];
    const float* b2        = (const float*)d_in[12];
    const float* gamma     = (const float*)d_in[13];
    const float* beta      = (const float*)d_in[14];
    const float* ew1       = (const float*)d_in[15];
    const float* eb1       = (const float*)d_in[16];
    const float* ew2       = (const float*)d_in[17];
    const float* eb2       = (const float*)d_in[18];
    const float* mw1       = (const float*)d_in[19];
    const float* mb1       = (const float*)d_in[20];
    const float* mw2       = (const float*)d_in[21];
    const float* mb2       = (const float*)d_in[22];
    const float* mw3       = (const float*)d_in[23];
    const float* mb3       = (const float*)d_in[24];
    float* out = (float*)d_out;

    // workspace layout (floats)
    float* e     = (float*)d_ws;                           // E*100
    float* tmp   = e   + (size_t)N_EDGES * HDIM;           // E*100 (also z, f1, f2)
    float* h     = tmp + (size_t)N_EDGES * HDIM;           // N*100
    float* agg   = h   + (size_t)N_NODES * HDIM;           // N*100
    float* stats = agg + (size_t)N_NODES * HDIM;           // 256
    float* z  = tmp;                                       // alias (N*100 <= E*100)
    float* f1 = tmp;                                       // E*50
    float* f2 = tmp + (size_t)N_EDGES * 50;                // E*25

    const int* srcp = ei;
    const int* dstp = ei + N_EDGES;
    dim3 blk(256);

    // 1. h = x @ node_w + node_b          [N,128]@[128,100]
    gemm_k<100,112,0,0,true><<<gblocks(N_NODES), blk, 0, stream>>>(
        x, node_w, node_b, h, N_NODES, 128, nullptr, nullptr, nullptr, nullptr);
    // 2. e = edge_attr @ edge_w + edge_b  [E,64]@[64,100]
    gemm_k<100,112,0,0,true><<<gblocks(N_EDGES), blk, 0, stream>>>(
        edge_attr, edge_w, edge_b, e, N_EDGES, 64, nullptr, nullptr, nullptr, nullptr);

    for (int i = 0; i < 2; ++i) {
        // 3. tmp = e @ lin_w[i] + lin_b[i]
        gemm_k<100,112,0,0,true><<<gblocks(N_EDGES), blk, 0, stream>>>(
            e, lin_w + (size_t)i * HDIM * HDIM, lin_b + i * HDIM, tmp,
            N_EDGES, HDIM, nullptr, nullptr, nullptr, nullptr);
        // 4. agg = h   (folds the (1+eps)*x term, eps=0)
        hipMemcpyAsync(agg, h, (size_t)N_NODES * HDIM * sizeof(float),
                       hipMemcpyDeviceToDevice, stream);
        // 5. agg[dst] += relu(h[src] + tmp)
        msg_scatter_k<<<(N_EDGES * HDIM) / 256, blk, 0, stream>>>(h, tmp, srcp, dstp, agg);
        // 6. z = relu(agg @ w1[i] + b1[i])
        gemm_k<100,112,1,0,true><<<gblocks(N_NODES), blk, 0, stream>>>(
            agg, w1 + (size_t)i * HDIM * HDIM, b1 + i * HDIM, z,
            N_NODES, HDIM, nullptr, nullptr, nullptr, nullptr);
        // 7. agg = z @ w2[i] + b2[i]
        gemm_k<100,112,0,0,true><<<gblocks(N_NODES), blk, 0, stream>>>(
            z, w2 + (size_t)i * HDIM * HDIM, b2 + i * HDIM, agg,
            N_NODES, HDIM, nullptr, nullptr, nullptr, nullptr);
        // 8. BN stats
        hipMemsetAsync(stats, 0, 2 * HDIM * sizeof(float), stream);
        bn_stats_k<<<1024, dim3(128), 0, stream>>>(agg, stats);
        // 9. h = (h + relu(BN(agg))) / 2
        bn_apply_k<<<(N_NODES * HDIM + 255) / 256, blk, 0, stream>>>(
            agg, stats, gamma + i * HDIM, beta + i * HDIM, h);
        // 10. tmp = relu(cat(h[src],h[dst],e) @ ew1[i] + eb1[i])
        gemm_k<100,112,1,1,true><<<gblocks(N_EDGES), blk, 0, stream>>>(
            nullptr, ew1 + (size_t)i * 3 * HDIM * HDIM, eb1 + i * HDIM, tmp,
            N_EDGES, 3 * HDIM, srcp, dstp, h, e);
        // 11. e = e + 0.5*(tmp @ ew2[i] + eb2[i])
        gemm_k<100,112,2,0,true><<<gblocks(N_EDGES), blk, 0, stream>>>(
            tmp, ew2 + (size_t)i * HDIM * HDIM, eb2 + i * HDIM, e,
            N_EDGES, HDIM, nullptr, nullptr, nullptr, nullptr);
    }

    // 12. f1 = relu(cat(relu(h[src]),relu(h[dst]),e) @ mw1 + mb1)   [E,300]@[300,50]
    gemm_k<50,64,1,2,true><<<gblocks(N_EDGES), blk, 0, stream>>>(
        nullptr, mw1, mb1, f1, N_EDGES, 3 * HDIM, srcp, dstp, h, e);
    // 13. f2 = relu(f1 @ mw2 + mb2)   [E,50]@[50,25]  (K=50 not /4 -> scalar loads)
    gemm_k<25,32,1,0,false><<<gblocks(N_EDGES), blk, 0, stream>>>(
        f1, mw2, mb2, f2, N_EDGES, 50, nullptr, nullptr, nullptr, nullptr);
    // 14. out = f2 @ mw3 + mb3        [E,25]@[25,2]
    final_out_k<<<N_EDGES / 256, blk, 0, stream>>>(f2, mw3, mb3, out);
}

// Round 3
// 6319.221 us; speedup vs baseline: 2.0951x; 2.0951x over previous
//
#include <hip/hip_runtime.h>

#define N_NODES 100000
#define N_EDGES 800000
#define HDIM 100

constexpr int RT   = 64;    // rows per block tile
constexpr int KCH  = 100;   // K chunk staged in LDS
constexpr int APAD = 104;   // padded A tile row (floats)

// C[M,NC] = epilogue(A[M,K] @ W[K,NC] + bias)
// MODE:   0 = store, 1 = relu+store, 2 = C += 0.5*v
// GATHER: 0 = plain A; 1 = row m = cat(h[src],h[dst],e); 2 = same + relu on h segs
// VEC:    4 = float4 A loads (K-chunks %4), 2 = float2 (K=50)
template<int NC, int NCP, int MODE, int GATHER, int VEC>
__global__ __launch_bounds__(256, 2)
void gemm2_k(const float* __restrict__ A, const float* __restrict__ W,
             const float* __restrict__ bias, float* __restrict__ C,
             int M, int K,
             const int* __restrict__ src, const int* __restrict__ dst,
             const float* __restrict__ hbuf, const float* __restrict__ ebuf)
{
    constexpr int CG  = NCP / 4;      // col groups (threads across cols)
    constexpr int RG  = 256 / CG;     // row groups
    constexpr int RPT = RT / RG;      // rows per thread
    static_assert(CG * RG == 256, "bad geometry");

    __shared__ float As[RT * APAD];
    __shared__ float Ws[KCH * NCP];
    __shared__ int   sidx[RT], didx[RT];

    const int tid = threadIdx.x;
    const int cg  = tid % CG;
    const int rg  = tid / CG;
    const long row0 = (long)blockIdx.x * RT;

    if (GATHER) {
        if (tid < RT && row0 + tid < M) {
            sidx[tid] = src[row0 + tid];
            didx[tid] = dst[row0 + tid];
        }
        __syncthreads();
    }

    float acc[RPT][4];
#pragma unroll
    for (int r = 0; r < RPT; ++r)
#pragma unroll
        for (int j = 0; j < 4; ++j) acc[r][j] = 0.f;

    for (int k0 = 0; k0 < K; k0 += KCH) {
        const int kc  = (K - k0 < KCH) ? (K - k0) : KCH;
        const int nk4 = (kc + 3) >> 2;

        // ---- stage A tile (coalesced, contiguous within rows) ----
        if (GATHER) {
            const int seg = k0 / 100;                 // 0:h[src] 1:h[dst] 2:e
            const float* base = (seg == 2) ? ebuf : hbuf;
            for (int j = tid; j < RT * 25; j += 256) {
                int r = j / 25, c4 = (j % 25) * 4;
                long grow = row0 + r;
                float4 v = make_float4(0.f, 0.f, 0.f, 0.f);
                if (grow < M) {
                    long rr = (seg == 0) ? (long)sidx[r]
                            : (seg == 1) ? (long)didx[r] : grow;
                    v = *(const float4*)&base[rr * HDIM + c4];
                    if (GATHER == 2 && seg < 2) {
                        v.x = fmaxf(v.x, 0.f); v.y = fmaxf(v.y, 0.f);
                        v.z = fmaxf(v.z, 0.f); v.w = fmaxf(v.w, 0.f);
                    }
                }
                *(float4*)&As[r * APAD + c4] = v;
            }
        } else if (VEC == 4) {
            const int kf4 = kc >> 2;                  // kc %4 == 0 on this path
            for (int j = tid; j < RT * kf4; j += 256) {
                int r = j / kf4, c4 = (j % kf4) * 4;
                long grow = row0 + r;
                float4 v = make_float4(0.f, 0.f, 0.f, 0.f);
                if (grow < M) v = *(const float4*)&A[grow * (long)K + k0 + c4];
                *(float4*)&As[r * APAD + c4] = v;
            }
        } else {                                       // VEC == 2 (K=50)
            const int kf2 = kc >> 1;
            for (int j = tid; j < RT * kf2; j += 256) {
                int r = j / kf2, c2 = (j % kf2) * 2;
                long grow = row0 + r;
                float2 v = make_float2(0.f, 0.f);
                if (grow < M) v = *(const float2*)&A[grow * (long)K + k0 + c2];
                *(float2*)&As[r * APAD + c2] = v;
            }
            if (kc & 3) {                              // zero k-pad words
                for (int j = tid; j < RT * 2; j += 256)
                    As[(j >> 1) * APAD + kc + (j & 1)] = 0.f;
            }
        }

        // ---- stage W tile (zero-padded to NCP cols and 4k rows) ----
        for (int j = tid; j < nk4 * 4 * (NCP / 4); j += 256) {
            int kk = j / (NCP / 4);
            int c4 = (j % (NCP / 4)) * 4;
            float4 v = make_float4(0.f, 0.f, 0.f, 0.f);
            if (kk < kc) {
                if (NC % 4 == 0) {
                    if (c4 < NC) v = *(const float4*)&W[(long)(k0 + kk) * NC + c4];
                } else {
                    if (c4 + 0 < NC) v.x = W[(long)(k0 + kk) * NC + c4 + 0];
                    if (c4 + 1 < NC) v.y = W[(long)(k0 + kk) * NC + c4 + 1];
                    if (c4 + 2 < NC) v.z = W[(long)(k0 + kk) * NC + c4 + 2];
                    if (c4 + 3 < NC) v.w = W[(long)(k0 + kk) * NC + c4 + 3];
                }
            }
            *(float4*)&Ws[kk * NCP + c4] = v;
        }
        __syncthreads();

        // ---- inner: A broadcast x W b128, 16 FMA per (r,k4) ----
        const float4* Af4 = (const float4*)As;
        const float4* Wf4 = (const float4*)Ws;
        for (int k4 = 0; k4 < nk4; ++k4) {
            float4 w0 = Wf4[(k4 * 4 + 0) * (NCP / 4) + cg];
            float4 w1 = Wf4[(k4 * 4 + 1) * (NCP / 4) + cg];
            float4 w2 = Wf4[(k4 * 4 + 2) * (NCP / 4) + cg];
            float4 w3 = Wf4[(k4 * 4 + 3) * (NCP / 4) + cg];
#pragma unroll
            for (int r = 0; r < RPT; ++r) {
                float4 a = Af4[(rg * RPT + r) * (APAD / 4) + k4];
                acc[r][0] += a.x * w0.x + a.y * w1.x + a.z * w2.x + a.w * w3.x;
                acc[r][1] += a.x * w0.y + a.y * w1.y + a.z * w2.y + a.w * w3.y;
                acc[r][2] += a.x * w0.z + a.y * w1.z + a.z * w2.z + a.w * w3.z;
                acc[r][3] += a.x * w0.w + a.y * w1.w + a.z * w2.w + a.w * w3.w;
            }
        }
        __syncthreads();
    }

    // ---- epilogue: coalesced float4 stores ----
    const int c0 = cg * 4;
    if (NC % 4 == 0) {
        if (c0 < NC) {
            float4 bv = *(const float4*)&bias[c0];
#pragma unroll
            for (int r = 0; r < RPT; ++r) {
                long grow = row0 + rg * RPT + r;
                if (grow >= M) continue;
                float4 v;
                v.x = acc[r][0] + bv.x; v.y = acc[r][1] + bv.y;
                v.z = acc[r][2] + bv.z; v.w = acc[r][3] + bv.w;
                if (MODE == 1) {
                    v.x = fmaxf(v.x, 0.f); v.y = fmaxf(v.y, 0.f);
                    v.z = fmaxf(v.z, 0.f); v.w = fmaxf(v.w, 0.f);
                }
                float4* cp = (float4*)&C[grow * (long)NC + c0];
                if (MODE == 2) {
                    float4 cur = *cp;
                    v.x = cur.x + 0.5f * v.x; v.y = cur.y + 0.5f * v.y;
                    v.z = cur.z + 0.5f * v.z; v.w = cur.w + 0.5f * v.w;
                }
                *cp = v;
            }
        }
    } else {
#pragma unroll
        for (int r = 0; r < RPT; ++r) {
            long grow = row0 + rg * RPT + r;
            if (grow >= M) continue;
#pragma unroll
            for (int j = 0; j < 4; ++j) {
                int c = c0 + j;
                if (c < NC) {
                    float v = acc[r][j] + bias[c];
                    if (MODE == 1) v = fmaxf(v, 0.f);
                    long o = grow * (long)NC + c;
                    if (MODE == 2) C[o] = C[o] + 0.5f * v;
                    else           C[o] = v;
                }
            }
        }
    }
}

// msg = relu(h[src] + lin_e);  agg[dst] += msg   (agg pre-initialized with h)
__global__ __launch_bounds__(256)
void msg_scatter_k(const float* __restrict__ h, const float* __restrict__ tmp,
                   const int* __restrict__ src, const int* __restrict__ dst,
                   float* __restrict__ agg)
{
    unsigned idx = blockIdx.x * 256u + threadIdx.x;   // < E*100 = 80M
    unsigned m = idx / HDIM;
    unsigned c = idx - m * HDIM;
    int s = src[m], d = dst[m];
    float v = fmaxf(h[(long)s * HDIM + c] + tmp[idx], 0.f);
    atomicAdd(&agg[(long)d * HDIM + c], v);
}

__global__ __launch_bounds__(128)
void bn_stats_k(const float* __restrict__ z, float* __restrict__ stats)
{
    int c = threadIdx.x;
    if (c >= HDIM) return;
    long rows_per = (N_NODES + gridDim.x - 1) / gridDim.x;
    long r0 = (long)blockIdx.x * rows_per;
    long r1 = r0 + rows_per; if (r1 > N_NODES) r1 = N_NODES;
    float s = 0.f, s2 = 0.f;
    for (long r = r0; r < r1; ++r) {
        float v = z[r * HDIM + c];
        s += v; s2 += v * v;
    }
    atomicAdd(&stats[c], s);
    atomicAdd(&stats[HDIM + c], s2);
}

__global__ __launch_bounds__(256)
void bn_apply_k(const float* __restrict__ z, const float* __restrict__ stats,
                const float* __restrict__ gamma, const float* __restrict__ beta,
                float* __restrict__ h)
{
    unsigned idx = blockIdx.x * 256u + threadIdx.x;
    if (idx >= (unsigned)(N_NODES * HDIM)) return;
    unsigned c = idx % HDIM;
    const float invN = 1.f / N_NODES;
    float mu  = stats[c] * invN;
    float var = stats[HDIM + c] * invN - mu * mu;
    float v = (z[idx] - mu) * rsqrtf(var + 1e-5f) * gamma[c] + beta[c];
    h[idx] = (h[idx] + fmaxf(v, 0.f)) * 0.5f;
}

// out[E,2] = f2[E,25] @ mw3[25,2] + mb3
__global__ __launch_bounds__(256)
void final_out_k(const float* __restrict__ f2, const float* __restrict__ W,
                 const float* __restrict__ b, float* __restrict__ out)
{
    unsigned m = blockIdx.x * 256u + threadIdx.x;
    if (m >= N_EDGES) return;
    float a0 = b[0], a1 = b[1];
    const float* row = &f2[(long)m * 25];
#pragma unroll
    for (int k = 0; k < 25; ++k) {
        float v = row[k];
        a0 += v * W[k * 2 + 0];
        a1 += v * W[k * 2 + 1];
    }
    out[(long)m * 2 + 0] = a0;
    out[(long)m * 2 + 1] = a1;
}

static inline int gblocks(long m) { return (int)((m + RT - 1) / RT); }

extern "C" void kernel_launch(void* const* d_in, const int* in_sizes, int n_in,
                              void* d_out, int out_size, void* d_ws, size_t ws_size,
                              hipStream_t stream)
{
    const float* x         = (const float*)d_in[0];
    const int*   ei        = (const int*)  d_in[1];
    const float* edge_attr = (const float*)d_in[2];
    const float* node_w    = (const float*)d_in[3];
    const float* node_b    = (const float*)d_in[4];
    const float* edge_w    = (const float*)d_in[5];
    const float* edge_b    = (const float*)d_in[6];
    const float* lin_w     = (const float*)d_in[7];
    const float* lin_b     = (const float*)d_in[8];
    const float* w1        = (const float*)d_in[9];
    const float* b1        = (const float*)d_in[10];
    const float* w2        = (const float*)d_in[11];
    const float* b2        = (const float*)d_in[12];
    const float* gamma     = (const float*)d_in[13];
    const float* beta      = (const float*)d_in[14];
    const float* ew1       = (const float*)d_in[15];
    const float* eb1       = (const float*)d_in[16];
    const float* ew2       = (const float*)d_in[17];
    const float* eb2       = (const float*)d_in[18];
    const float* mw1       = (const float*)d_in[19];
    const float* mb1       = (const float*)d_in[20];
    const float* mw2       = (const float*)d_in[21];
    const float* mb2       = (const float*)d_in[22];
    const float* mw3       = (const float*)d_in[23];
    const float* mb3       = (const float*)d_in[24];
    float* out = (float*)d_out;

    // workspace layout (floats)
    float* e     = (float*)d_ws;                           // E*100
    float* tmp   = e   + (size_t)N_EDGES * HDIM;           // E*100 (also z, f1, f2)
    float* h     = tmp + (size_t)N_EDGES * HDIM;           // N*100
    float* agg   = h   + (size_t)N_NODES * HDIM;           // N*100
    float* stats = agg + (size_t)N_NODES * HDIM;           // 256
    float* z  = tmp;                                       // alias
    float* f1 = tmp;                                       // E*50
    float* f2 = tmp + (size_t)N_EDGES * 50;                // E*25

    const int* srcp = ei;
    const int* dstp = ei + N_EDGES;
    dim3 blk(256);

    // 1. h = x @ node_w + node_b          [N,128]@[128,100]
    gemm2_k<100,128,0,0,4><<<gblocks(N_NODES), blk, 0, stream>>>(
        x, node_w, node_b, h, N_NODES, 128, nullptr, nullptr, nullptr, nullptr);
    // 2. e = edge_attr @ edge_w + edge_b  [E,64]@[64,100]
    gemm2_k<100,128,0,0,4><<<gblocks(N_EDGES), blk, 0, stream>>>(
        edge_attr, edge_w, edge_b, e, N_EDGES, 64, nullptr, nullptr, nullptr, nullptr);

    for (int i = 0; i < 2; ++i) {
        // 3. tmp = e @ lin_w[i] + lin_b[i]
        gemm2_k<100,128,0,0,4><<<gblocks(N_EDGES), blk, 0, stream>>>(
            e, lin_w + (size_t)i * HDIM * HDIM, lin_b + i * HDIM, tmp,
            N_EDGES, HDIM, nullptr, nullptr, nullptr, nullptr);
        // 4. agg = h   (folds (1+eps)*x, eps=0)
        hipMemcpyAsync(agg, h, (size_t)N_NODES * HDIM * sizeof(float),
                       hipMemcpyDeviceToDevice, stream);
        // 5. agg[dst] += relu(h[src] + tmp)
        msg_scatter_k<<<(N_EDGES * HDIM) / 256, blk, 0, stream>>>(h, tmp, srcp, dstp, agg);
        // 6. z = relu(agg @ w1[i] + b1[i])
        gemm2_k<100,128,1,0,4><<<gblocks(N_NODES), blk, 0, stream>>>(
            agg, w1 + (size_t)i * HDIM * HDIM, b1 + i * HDIM, z,
            N_NODES, HDIM, nullptr, nullptr, nullptr, nullptr);
        // 7. agg = z @ w2[i] + b2[i]
        gemm2_k<100,128,0,0,4><<<gblocks(N_NODES), blk, 0, stream>>>(
            z, w2 + (size_t)i * HDIM * HDIM, b2 + i * HDIM, agg,
            N_NODES, HDIM, nullptr, nullptr, nullptr, nullptr);
        // 8. BN stats
        hipMemsetAsync(stats, 0, 2 * HDIM * sizeof(float), stream);
        bn_stats_k<<<1024, dim3(128), 0, stream>>>(agg, stats);
        // 9. h = (h + relu(BN(agg))) / 2
        bn_apply_k<<<(N_NODES * HDIM + 255) / 256, blk, 0, stream>>>(
            agg, stats, gamma + i * HDIM, beta + i * HDIM, h);
        // 10. tmp = relu(cat(h[src],h[dst],e) @ ew1[i] + eb1[i])   K=300
        gemm2_k<100,128,1,1,4><<<gblocks(N_EDGES), blk, 0, stream>>>(
            nullptr, ew1 + (size_t)i * 3 * HDIM * HDIM, eb1 + i * HDIM, tmp,
            N_EDGES, 3 * HDIM, srcp, dstp, h, e);
        // 11. e = e + 0.5*(tmp @ ew2[i] + eb2[i])
        gemm2_k<100,128,2,0,4><<<gblocks(N_EDGES), blk, 0, stream>>>(
            tmp, ew2 + (size_t)i * HDIM * HDIM, eb2 + i * HDIM, e,
            N_EDGES, HDIM, nullptr, nullptr, nullptr, nullptr);
    }

    // 12. f1 = relu(cat(relu(h[src]),relu(h[dst]),e) @ mw1 + mb1)  [E,300]@[300,50]
    gemm2_k<50,64,1,2,4><<<gblocks(N_EDGES), blk, 0, stream>>>(
        nullptr, mw1, mb1, f1, N_EDGES, 3 * HDIM, srcp, dstp, h, e);
    // 13. f2 = relu(f1 @ mw2 + mb2)   [E,50]@[50,25]
    gemm2_k<25,32,1,0,2><<<gblocks(N_EDGES), blk, 0, stream>>>(
        f1, mw2, mb2, f2, N_EDGES, 50, nullptr, nullptr, nullptr, nullptr);
    // 14. out = f2 @ mw3 + mb3        [E,25]@[25,2]
    final_out_k<<<N_EDGES / 256, blk, 0, stream>>>(f2, mw3, mb3, out);
}